// Round 8
// baseline (564.262 us; speedup 1.0000x reference)
//
#include <hip/hip_runtime.h>
#include <hip/hip_bf16.h>

// Fused LayerNorm + QKV projection for B=4, S=2048, H=2048 (fp32 in/out).
//
// Round 8: 256x256/BK=64/8-wave, r3's proven stage+vmcnt ledger, with
// (a) A-only register lookahead (x/y) + single B set (cb) -> ~130 VGPR +
//     128 AGPR, inside the 256-unified cap (r7 spilled at 264: the
//     regression mechanism), and
// (b) even/odd wave ORDER SWAP per phase: even waves [reads->MFMA], odd
//     waves [MFMA->reads], so the LDS pipe and matrix pipe overlap instead
//     of CU-wide alternation (r3/r6: phase = LDS 700 + MFMA 515 serialized).

#define HD   2048            // hidden dim (K)
#define MTOT 8192            // B*S rows
#define NTOT 6144            // 3*H packed output cols
#define NIT  16              // iterations (2 K-tiles of BK=64 each)

typedef __attribute__((ext_vector_type(8))) _Float16 f16x8;   // 4 VGPR
typedef __attribute__((ext_vector_type(4))) _Float16 f16x4;
typedef __attribute__((ext_vector_type(4))) float f32x4;

// ---------------------------------------------------------------------------
// Kernel 1: LayerNorm -> fp16.  One block per row, 256 threads, 8 elems each.
// ---------------------------------------------------------------------------
__global__ __launch_bounds__(256) void ln_f16_kernel(
    const float* __restrict__ x, const float* __restrict__ gamma,
    const float* __restrict__ beta, _Float16* __restrict__ hi) {
  const int row = blockIdx.x;
  const float* xr = x + (size_t)row * HD;
  const int t = threadIdx.x;

  float4 v0 = reinterpret_cast<const float4*>(xr)[t * 2];
  float4 v1 = reinterpret_cast<const float4*>(xr)[t * 2 + 1];
  float xs[8] = {v0.x, v0.y, v0.z, v0.w, v1.x, v1.y, v1.z, v1.w};

  float s = 0.f, q = 0.f;
#pragma unroll
  for (int j = 0; j < 8; ++j) { s += xs[j]; q += xs[j] * xs[j]; }
#pragma unroll
  for (int off = 32; off; off >>= 1) {
    s += __shfl_down(s, off);
    q += __shfl_down(q, off);
  }
  __shared__ float red[8];
  const int wid = t >> 6, lane = t & 63;
  if (lane == 0) { red[wid] = s; red[4 + wid] = q; }
  __syncthreads();
  s = red[0] + red[1] + red[2] + red[3];
  q = red[4] + red[5] + red[6] + red[7];
  const float mu  = s * (1.f / HD);
  const float var = q * (1.f / HD) - mu * mu;
  const float rs  = rsqrtf(var + 1e-5f);

  float4 g0 = reinterpret_cast<const float4*>(gamma)[t * 2];
  float4 g1 = reinterpret_cast<const float4*>(gamma)[t * 2 + 1];
  float4 b0 = reinterpret_cast<const float4*>(beta)[t * 2];
  float4 b1 = reinterpret_cast<const float4*>(beta)[t * 2 + 1];
  float gs[8] = {g0.x, g0.y, g0.z, g0.w, g1.x, g1.y, g1.z, g1.w};
  float bs[8] = {b0.x, b0.y, b0.z, b0.w, b1.x, b1.y, b1.z, b1.w};

  f16x8 hv;
#pragma unroll
  for (int j = 0; j < 8; ++j) {
    float y = (xs[j] - mu) * rs * gs[j] + bs[j];
    hv[j] = (_Float16)y;
  }
  *reinterpret_cast<f16x8*>(&hi[(size_t)row * HD + t * 8]) = hv;
}

// ---------------------------------------------------------------------------
// Kernel 2: weights -> fp16 (q, k, v stacked).
// ---------------------------------------------------------------------------
__global__ __launch_bounds__(256) void w_f16_kernel(
    const float* __restrict__ qw, const float* __restrict__ kw,
    const float* __restrict__ vw, _Float16* __restrict__ hi) {
  const int m = blockIdx.y;
  const float* src = (m == 0) ? qw : (m == 1) ? kw : vw;
  const size_t base = (size_t)m * HD * HD;
  const int total4 = HD * HD / 4;
  for (int i = blockIdx.x * blockDim.x + threadIdx.x; i < total4;
       i += gridDim.x * blockDim.x) {
    float4 v = reinterpret_cast<const float4*>(src)[i];
    f16x4 hv;
    hv[0] = (_Float16)v.x; hv[1] = (_Float16)v.y;
    hv[2] = (_Float16)v.z; hv[3] = (_Float16)v.w;
    *reinterpret_cast<f16x4*>(&hi[base + (size_t)i * 4]) = hv;
  }
}

// ---------------------------------------------------------------------------
// Kernel 3: 256x256 8-phase fp16 GEMM, A-lookahead + even/odd order swap.
// out[m][n] = sum_k A[m][k] * W_p[n][k] + bias_p[n]
//
// LDS (128 KiB, f16 units): A bufs at {0, 16384}, B bufs at {32768, 49152};
// buffer = 8 kb-planes x 256 rows x 8 f16 (linear for global_load_lds,
// conflict-free ds_read_b128 - 0 conflicts measured r1-r7).
//
// Stage slots + vmcnt(6) ledger = r3 (passed twice):
//   P0: buf1.A-mh1<-kt1 | P1: buf0.B-h0<-kt2 | P2: buf0.B-h1 |
//   P3: buf0.A-mh0 +VM6(proves buf1) | P4: buf0.A-mh1 | P5: buf1.B-h0<-kt3 |
//   P6: buf1.B-h1 | P7: buf1.A-mh0 +VM6(proves buf0@kt2).
//   Last iteration: P3 uses VM0 (skipped stages break the vmcnt(6) proof).
// B-frags (cb) load in-phase at P0/P4 (the K-tile's first phase, region
// proven by the prior guard); A-frags alternate x/y one phase ahead.
// Even waves: [reads -> MFMA]; odd waves: [MFMA -> reads] (wave-uniform
// branch, same barrier count) -> LDS pipe and matrix pipe overlap.
// ---------------------------------------------------------------------------
__device__ __forceinline__ void gload16(const _Float16* g, _Float16* l) {
  __builtin_amdgcn_global_load_lds(
      (const __attribute__((address_space(1))) void*)g,
      (__attribute__((address_space(3))) void*)l, 16, 0, 0);
}

#define BAR()   asm volatile("s_barrier" ::: "memory")
#define LGKM0() asm volatile("s_waitcnt lgkmcnt(0)" ::: "memory")
#define VM6()   asm volatile("s_waitcnt vmcnt(6)" ::: "memory")
#define VM0()   asm volatile("s_waitcnt vmcnt(0)" ::: "memory")

#define LA(BUF, X, MH, KS) \
  (*(const f16x8*)(lds + (BUF)*16384 + rA + (KS)*8192 + (MH)*512 + (X)*128))
#define LB(BUF, NR, KS) \
  (*(const f16x8*)(lds + 32768 + (BUF)*16384 + rB + (KS)*8192 + (NR)*128))

#define ALD(T0, T1, T2, T3, BUF, MH, KS) do { \
    T0 = LA(BUF, 0, MH, KS); T1 = LA(BUF, 1, MH, KS); \
    T2 = LA(BUF, 2, MH, KS); T3 = LA(BUF, 3, MH, KS); \
  } while (0)

#define BLD(BUF) do { \
    cb[0][0]=LB(BUF,0,0); cb[1][0]=LB(BUF,1,0); \
    cb[2][0]=LB(BUF,2,0); cb[3][0]=LB(BUF,3,0); \
    cb[0][1]=LB(BUF,0,1); cb[1][1]=LB(BUF,1,1); \
    cb[2][1]=LB(BUF,2,1); cb[3][1]=LB(BUF,3,1); \
  } while (0)

#define MF(A, B, C) __builtin_amdgcn_mfma_f32_16x16x32_f16(A, B, C, 0, 0, 0)

#define MFMAS(A0, A1, A2, A3, MH, KS) do { \
    __builtin_amdgcn_s_setprio(1); \
    acc[(MH)*4+0][0]=MF(A0,cb[0][KS],acc[(MH)*4+0][0]); \
    acc[(MH)*4+0][1]=MF(A0,cb[1][KS],acc[(MH)*4+0][1]); \
    acc[(MH)*4+0][2]=MF(A0,cb[2][KS],acc[(MH)*4+0][2]); \
    acc[(MH)*4+0][3]=MF(A0,cb[3][KS],acc[(MH)*4+0][3]); \
    acc[(MH)*4+1][0]=MF(A1,cb[0][KS],acc[(MH)*4+1][0]); \
    acc[(MH)*4+1][1]=MF(A1,cb[1][KS],acc[(MH)*4+1][1]); \
    acc[(MH)*4+1][2]=MF(A1,cb[2][KS],acc[(MH)*4+1][2]); \
    acc[(MH)*4+1][3]=MF(A1,cb[3][KS],acc[(MH)*4+1][3]); \
    acc[(MH)*4+2][0]=MF(A2,cb[0][KS],acc[(MH)*4+2][0]); \
    acc[(MH)*4+2][1]=MF(A2,cb[1][KS],acc[(MH)*4+2][1]); \
    acc[(MH)*4+2][2]=MF(A2,cb[2][KS],acc[(MH)*4+2][2]); \
    acc[(MH)*4+2][3]=MF(A2,cb[3][KS],acc[(MH)*4+2][3]); \
    acc[(MH)*4+3][0]=MF(A3,cb[0][KS],acc[(MH)*4+3][0]); \
    acc[(MH)*4+3][1]=MF(A3,cb[1][KS],acc[(MH)*4+3][1]); \
    acc[(MH)*4+3][2]=MF(A3,cb[2][KS],acc[(MH)*4+3][2]); \
    acc[(MH)*4+3][3]=MF(A3,cb[3][KS],acc[(MH)*4+3][3]); \
    __builtin_amdgcn_s_setprio(0); \
  } while (0)

// Order-swapped phase: even waves reads-then-MFMA, odd waves MFMA-then-reads.
#define PH(ALDS, MFS) do { if (ev) { ALDS; MFS; } else { MFS; ALDS; } } while (0)

__global__ __launch_bounds__(512, 2) void qkv_gemm_kernel(
    const _Float16* __restrict__ Ah, const _Float16* __restrict__ Wh,
    const float* __restrict__ qb, const float* __restrict__ kb,
    const float* __restrict__ vb, float* __restrict__ out) {
  extern __shared__ _Float16 lds[];   // 131072 B

  const int t    = threadIdx.x;
  const int lane = t & 63;
  const int wid  = t >> 6;            // 0..7
  const int wm   = wid >> 2;          // 0..1 (M)
  const int wn   = wid & 3;           // 0..3 (N)
  const int fr   = lane & 15;
  const int fq   = lane >> 4;
  const bool ev  = (wid & 1) == 0;    // wave-uniform role split

  const int n0  = blockIdx.x * 256;
  const int m0  = blockIdx.y * 256;
  const int p   = n0 >> 11;
  const int ln0 = n0 & (HD - 1);
  const _Float16* Ag  = Ah + (size_t)m0 * HD;
  const _Float16* Bgp = Wh + (size_t)p * HD * HD + (size_t)ln0 * HD;
  const float* bias = (p == 0) ? qb : (p == 1) ? kb : vb;

  // staging invariants: wave-linear dest (chunk = kb0*256 + rowbase + lane)
  const int kb0     = t >> 7;                         // 0..3
  const int rowbase = (t & 63) + ((t & 64) << 1);     // lane + (wid&1)*128
  const size_t goff = (size_t)rowbase * HD + kb0 * 8; // global f16 offset
  const int ldsC    = kb0 * 256 + rowbase;            // lds chunk

  // fragment-read invariants (f16 offsets within a buffer)
  const int rA = fq * 2048 + wm * 1024 + fr * 8;
  const int rB = fq * 2048 + wn * 512 + fr * 8;

  auto stA = [&](int buf, int hf, int kt) {
    const _Float16* g = Ag + goff + (size_t)(hf * 64) * HD + kt * 64;
    _Float16* l = lds + buf * 16384 + (ldsC + hf * 64) * 8;
    gload16(g, l); gload16(g + 32, l + 8192);
  };
  auto stB = [&](int buf, int hf, int kt) {
    const _Float16* g = Bgp + goff + (size_t)(hf * 64) * HD + kt * 64;
    _Float16* l = lds + 32768 + buf * 16384 + (ldsC + hf * 64) * 8;
    gload16(g, l); gload16(g + 32, l + 8192);
  };

  f32x4 acc[8][4] = {};

  // Register state: A lookahead sets x/y (16+16 VGPR), single B set (32).
  f16x8 x0, x1, x2, x3;
  f16x8 y0, y1, y2, y3;
  f16x8 cb[4][2];

  // Prologue: buf0 <- K-tile 0 (4 halves), buf1 <- K-tile 1 (3 halves).
  // vmcnt(6) = 3 calls in flight -> buf0 fully landed.
  stB(0, 0, 0); stB(0, 1, 0); stA(0, 0, 0); stA(0, 1, 0);
  stB(1, 0, 1); stB(1, 1, 1); stA(1, 0, 1);
  VM6();
  BAR();
  ALD(x0, x1, x2, x3, 0, 0, 0);   // seed P0's A-frags

#pragma unroll 1
  for (int i = 0; i < NIT; ++i) {
    const bool nl = (i < NIT - 1);
    const int kt1 = 2 * i + 1, kt2 = 2 * i + 2, kt3 = 2 * i + 3;

    // ---- P0: BLD(buf0) in-phase; MFMA buf0(mh0,ks0) ----
    stA(1, 1, kt1);
    BLD(0);
    ALD(y0, y1, y2, y3, 0, 0, 1);
    MFMAS(x0, x1, x2, x3, 0, 0);
    LGKM0(); BAR();

    // ---- P1: MFMA buf0(mh0,ks1); lookahead A(0,mh1,ks0) ----
    if (nl) stB(0, 0, kt2);
    PH(ALD(x0, x1, x2, x3, 0, 1, 0),
       MFMAS(y0, y1, y2, y3, 0, 1));
    LGKM0(); BAR();

    // ---- P2: MFMA buf0(mh1,ks0); lookahead A(0,mh1,ks1) ----
    if (nl) stB(0, 1, kt2);
    PH(ALD(y0, y1, y2, y3, 0, 1, 1),
       MFMAS(x0, x1, x2, x3, 1, 0));
    LGKM0(); BAR();

    // ---- P3: MFMA buf0(mh1,ks1); guard buf1; lookahead A(1,mh0,ks0) ----
    if (nl) stA(0, 0, kt2);
    if (nl) {
      PH({ VM6(); ALD(x0, x1, x2, x3, 1, 0, 0); },
         MFMAS(y0, y1, y2, y3, 1, 1));
    } else {
      PH({ VM0(); ALD(x0, x1, x2, x3, 1, 0, 0); },
         MFMAS(y0, y1, y2, y3, 1, 1));
    }
    LGKM0(); BAR();

    // ---- P4: BLD(buf1) in-phase; MFMA buf1(mh0,ks0) ----
    if (nl) stA(0, 1, kt2);
    BLD(1);
    ALD(y0, y1, y2, y3, 1, 0, 1);
    MFMAS(x0, x1, x2, x3, 0, 0);
    LGKM0(); BAR();

    // ---- P5: MFMA buf1(mh0,ks1); lookahead A(1,mh1,ks0) ----
    if (nl) stB(1, 0, kt3);
    PH(ALD(x0, x1, x2, x3, 1, 1, 0),
       MFMAS(y0, y1, y2, y3, 0, 1));
    LGKM0(); BAR();

    // ---- P6: MFMA buf1(mh1,ks0); lookahead A(1,mh1,ks1) ----
    if (nl) stB(1, 1, kt3);
    PH(ALD(y0, y1, y2, y3, 1, 1, 1),
       MFMAS(x0, x1, x2, x3, 1, 0));
    LGKM0(); BAR();

    // ---- P7: MFMA buf1(mh1,ks1); guard buf0@kt2; lookahead A(0',mh0,ks0) --
    if (nl) {
      stA(1, 0, kt3);
      PH({ VM6(); ALD(x0, x1, x2, x3, 0, 0, 0); },
         MFMAS(y0, y1, y2, y3, 1, 1));
    } else {
      MFMAS(y0, y1, y2, y3, 1, 1);
    }
    LGKM0(); BAR();
  }

  // Epilogue: C/D layout col = lane&15, row = (lane>>4)*4 + reg.
  float bv[4];
#pragma unroll
  for (int nr = 0; nr < 4; ++nr)
    bv[nr] = bias[(ln0 + wn * 64 + nr * 16 + fr)];
#pragma unroll
  for (int mr = 0; mr < 8; ++mr) {
    const int r0 = m0 + wm * 128 + mr * 16 + fq * 4;
#pragma unroll
    for (int nr = 0; nr < 4; ++nr) {
      const int cg = n0 + wn * 64 + nr * 16 + fr;
      f32x4 v = acc[mr][nr];
#pragma unroll
      for (int r = 0; r < 4; ++r)
        out[(size_t)(r0 + r) * NTOT + cg] = v[r] + bv[nr];
    }
  }
}

// ---------------------------------------------------------------------------
extern "C" void kernel_launch(void* const* d_in, const int* in_sizes, int n_in,
                              void* d_out, int out_size, void* d_ws,
                              size_t ws_size, hipStream_t stream) {
  const float* x     = (const float*)d_in[0];
  const float* gamma = (const float*)d_in[1];
  const float* beta  = (const float*)d_in[2];
  const float* qw    = (const float*)d_in[3];
  const float* qb    = (const float*)d_in[4];
  const float* kw    = (const float*)d_in[5];
  const float* kbia  = (const float*)d_in[6];
  const float* vw    = (const float*)d_in[7];
  const float* vb    = (const float*)d_in[8];
  float* out = (float*)d_out;

  // Workspace: [0, 32M) normed fp16 [8192][2048]; [32M, 56M) W fp16 [3][2048][2048]
  char* ws = (char*)d_ws;
  _Float16* Ahp = (_Float16*)(ws);
  _Float16* Whp = (_Float16*)(ws + (size_t)MTOT * HD * 2);

  (void)hipFuncSetAttribute((const void*)qkv_gemm_kernel,
                            hipFuncAttributeMaxDynamicSharedMemorySize, 131072);

  ln_f16_kernel<<<MTOT, 256, 0, stream>>>(x, gamma, beta, Ahp);
  w_f16_kernel<<<dim3(1024, 3), 256, 0, stream>>>(qw, kw, vw, Whp);
  qkv_gemm_kernel<<<dim3(NTOT / 256, MTOT / 256), 512, 131072, stream>>>(
      Ahp, Whp, qb, kbia, vb, out);
}

// Round 10
// 267.246 us; speedup vs baseline: 2.1114x; 2.1114x over previous
//
#include <hip/hip_runtime.h>
#include <hip/hip_bf16.h>

// Fused LayerNorm + QKV projection for B=4, S=2048, H=2048 (fp32 in/out).
//
// Round 10 (= round 9 resubmitted after infra failure): r6 skeleton
// unchanged (256x256, BK=64, 8 waves, ephemeral fragments - r7/r8 proved
// persistent lookahead MUST spill at 128 AGPR acc), plus two L3-locality
// fixes:
//  (a) non-temporal epilogue stores: the 188 MB output stream was evicting
//      the 56 MB A/W working set from L3 every dispatch (FETCH_SIZE 176 MB
//      vs 56 MB logical) -> stage gloads ate HBM latency and stalled the
//      vmcnt(6) pipeline at P3/P7.
//  (b) XCD-chunked bijective swizzle (96 wg/XCD, n-fastest in 4x24 chunks):
//      concurrently-resident blocks on an XCD share A-panels 24-way -> L2.

#define HD   2048            // hidden dim (K)
#define MTOT 8192            // B*S rows
#define NTOT 6144            // 3*H packed output cols
#define NIT  16              // iterations (2 K-tiles of BK=64 each)

typedef __attribute__((ext_vector_type(8))) _Float16 f16x8;   // 4 VGPR
typedef __attribute__((ext_vector_type(4))) _Float16 f16x4;
typedef __attribute__((ext_vector_type(4))) float f32x4;

// ---------------------------------------------------------------------------
// Kernel 1: LayerNorm -> fp16.  One block per row, 256 threads, 8 elems each.
// ---------------------------------------------------------------------------
__global__ __launch_bounds__(256) void ln_f16_kernel(
    const float* __restrict__ x, const float* __restrict__ gamma,
    const float* __restrict__ beta, _Float16* __restrict__ hi) {
  const int row = blockIdx.x;
  const float* xr = x + (size_t)row * HD;
  const int t = threadIdx.x;

  float4 v0 = reinterpret_cast<const float4*>(xr)[t * 2];
  float4 v1 = reinterpret_cast<const float4*>(xr)[t * 2 + 1];
  float xs[8] = {v0.x, v0.y, v0.z, v0.w, v1.x, v1.y, v1.z, v1.w};

  float s = 0.f, q = 0.f;
#pragma unroll
  for (int j = 0; j < 8; ++j) { s += xs[j]; q += xs[j] * xs[j]; }
#pragma unroll
  for (int off = 32; off; off >>= 1) {
    s += __shfl_down(s, off);
    q += __shfl_down(q, off);
  }
  __shared__ float red[8];
  const int wid = t >> 6, lane = t & 63;
  if (lane == 0) { red[wid] = s; red[4 + wid] = q; }
  __syncthreads();
  s = red[0] + red[1] + red[2] + red[3];
  q = red[4] + red[5] + red[6] + red[7];
  const float mu  = s * (1.f / HD);
  const float var = q * (1.f / HD) - mu * mu;
  const float rs  = rsqrtf(var + 1e-5f);

  float4 g0 = reinterpret_cast<const float4*>(gamma)[t * 2];
  float4 g1 = reinterpret_cast<const float4*>(gamma)[t * 2 + 1];
  float4 b0 = reinterpret_cast<const float4*>(beta)[t * 2];
  float4 b1 = reinterpret_cast<const float4*>(beta)[t * 2 + 1];
  float gs[8] = {g0.x, g0.y, g0.z, g0.w, g1.x, g1.y, g1.z, g1.w};
  float bs[8] = {b0.x, b0.y, b0.z, b0.w, b1.x, b1.y, b1.z, b1.w};

  f16x8 hv;
#pragma unroll
  for (int j = 0; j < 8; ++j) {
    float y = (xs[j] - mu) * rs * gs[j] + bs[j];
    hv[j] = (_Float16)y;
  }
  *reinterpret_cast<f16x8*>(&hi[(size_t)row * HD + t * 8]) = hv;
}

// ---------------------------------------------------------------------------
// Kernel 2: weights -> fp16 (q, k, v stacked).
// ---------------------------------------------------------------------------
__global__ __launch_bounds__(256) void w_f16_kernel(
    const float* __restrict__ qw, const float* __restrict__ kw,
    const float* __restrict__ vw, _Float16* __restrict__ hi) {
  const int m = blockIdx.y;
  const float* src = (m == 0) ? qw : (m == 1) ? kw : vw;
  const size_t base = (size_t)m * HD * HD;
  const int total4 = HD * HD / 4;
  for (int i = blockIdx.x * blockDim.x + threadIdx.x; i < total4;
       i += gridDim.x * blockDim.x) {
    float4 v = reinterpret_cast<const float4*>(src)[i];
    f16x4 hv;
    hv[0] = (_Float16)v.x; hv[1] = (_Float16)v.y;
    hv[2] = (_Float16)v.z; hv[3] = (_Float16)v.w;
    *reinterpret_cast<f16x4*>(&hi[base + (size_t)i * 4]) = hv;
  }
}

// ---------------------------------------------------------------------------
// Kernel 3: 256x256 8-phase fp16 GEMM (r6 skeleton + locality fixes).
// out[m][n] = sum_k A[m][k] * W_p[n][k] + bias_p[n]
//
// LDS (128 KiB, f16 units): A bufs at {0, 16384}, B bufs at {32768, 49152};
// buffer = 8 kb-planes x 256 rows x 8 f16 (linear for global_load_lds,
// conflict-free ds_read_b128 - 0 conflicts measured r1-r8).
//
// Phase = [stage issue][ds_reads][16 MFMA][lgkmcnt(0)][vm guard?][s_barrier].
// Stage slots + vmcnt(6) ledger = r3/r6 (passed):
//   P0: buf1.A-mh1<-kt1 | P1: buf0.B-h0<-kt2 | P2: buf0.B-h1 |
//   P3: buf0.A-mh0 +VM6(proves buf1; VM0 last iter) | P4: buf0.A-mh1 |
//   P5: buf1.B-h0<-kt3 | P6: buf1.B-h1 | P7: buf1.A-mh0 +VM6(proves buf0@kt2)
// ---------------------------------------------------------------------------
__device__ __forceinline__ void gload16(const _Float16* g, _Float16* l) {
  __builtin_amdgcn_global_load_lds(
      (const __attribute__((address_space(1))) void*)g,
      (__attribute__((address_space(3))) void*)l, 16, 0, 0);
}

#define BAR()   asm volatile("s_barrier" ::: "memory")
#define LGKM0() asm volatile("s_waitcnt lgkmcnt(0)" ::: "memory")
#define VM6()   asm volatile("s_waitcnt vmcnt(6)" ::: "memory")
#define VM0()   asm volatile("s_waitcnt vmcnt(0)" ::: "memory")

#define LA(BUF, X, MH, KS) \
  (*(const f16x8*)(lds + (BUF)*16384 + rA + (KS)*8192 + (MH)*512 + (X)*128))
#define LB(BUF, NR, KS) \
  (*(const f16x8*)(lds + 32768 + (BUF)*16384 + rB + (KS)*8192 + (NR)*128))

#define BLOAD(BUF) do { \
    bfr[0][0]=LB(BUF,0,0); bfr[1][0]=LB(BUF,1,0); \
    bfr[2][0]=LB(BUF,2,0); bfr[3][0]=LB(BUF,3,0); \
    bfr[0][1]=LB(BUF,0,1); bfr[1][1]=LB(BUF,1,1); \
    bfr[2][1]=LB(BUF,2,1); bfr[3][1]=LB(BUF,3,1); \
  } while (0)
#define ALOAD(BUF, MH, KS) do { \
    a0=LA(BUF,0,MH,KS); a1=LA(BUF,1,MH,KS); \
    a2=LA(BUF,2,MH,KS); a3=LA(BUF,3,MH,KS); \
  } while (0)

#define MM(MR, NR, AREG, KS) \
  acc[MR][NR] = __builtin_amdgcn_mfma_f32_16x16x32_f16( \
      AREG, bfr[NR][KS], acc[MR][NR], 0, 0, 0);
#define MFMAS(MH, KS) do { \
    __builtin_amdgcn_s_setprio(1); \
    MM((MH)*4+0, 0, a0, KS) MM((MH)*4+0, 1, a0, KS) \
    MM((MH)*4+0, 2, a0, KS) MM((MH)*4+0, 3, a0, KS) \
    MM((MH)*4+1, 0, a1, KS) MM((MH)*4+1, 1, a1, KS) \
    MM((MH)*4+1, 2, a1, KS) MM((MH)*4+1, 3, a1, KS) \
    MM((MH)*4+2, 0, a2, KS) MM((MH)*4+2, 1, a2, KS) \
    MM((MH)*4+2, 2, a2, KS) MM((MH)*4+2, 3, a2, KS) \
    MM((MH)*4+3, 0, a3, KS) MM((MH)*4+3, 1, a3, KS) \
    MM((MH)*4+3, 2, a3, KS) MM((MH)*4+3, 3, a3, KS) \
    __builtin_amdgcn_s_setprio(0); \
  } while (0)

__global__ __launch_bounds__(512, 2) void qkv_gemm_kernel(
    const _Float16* __restrict__ Ah, const _Float16* __restrict__ Wh,
    const float* __restrict__ qb, const float* __restrict__ kb,
    const float* __restrict__ vb, float* __restrict__ out) {
  extern __shared__ _Float16 lds[];   // 131072 B

  const int t    = threadIdx.x;
  const int lane = t & 63;
  const int wid  = t >> 6;            // 0..7
  const int wm   = wid >> 2;          // 0..1 (M)
  const int wn   = wid & 3;           // 0..3 (N)
  const int fr   = lane & 15;
  const int fq   = lane >> 4;

  // XCD-chunked bijective swizzle (768 wgs, 96/XCD): XCD x owns a 4x24
  // (m x n) chunk, n-fastest -> concurrently-resident blocks share A-panels.
  const int orig = blockIdx.y * gridDim.x + blockIdx.x;
  const int wg   = (orig & 7) * 96 + (orig >> 3);
  const int bx   = wg % 24;
  const int by   = wg / 24;

  const int n0  = bx * 256;
  const int m0  = by * 256;
  const int p   = n0 >> 11;
  const int ln0 = n0 & (HD - 1);
  const _Float16* Ag  = Ah + (size_t)m0 * HD;
  const _Float16* Bgp = Wh + (size_t)p * HD * HD + (size_t)ln0 * HD;
  const float* bias = (p == 0) ? qb : (p == 1) ? kb : vb;

  // staging invariants: wave-linear dest (chunk = kb0*256 + rowbase + lane)
  const int kb0     = t >> 7;                         // 0..3
  const int rowbase = (t & 63) + ((t & 64) << 1);     // lane + (wid&1)*128
  const size_t goff = (size_t)rowbase * HD + kb0 * 8; // global f16 offset
  const int ldsC    = kb0 * 256 + rowbase;            // lds chunk

  // fragment-read invariants (f16 offsets within a buffer)
  const int rA = fq * 2048 + wm * 1024 + fr * 8;
  const int rB = fq * 2048 + wn * 512 + fr * 8;

  auto stA = [&](int buf, int hf, int kt) {
    const _Float16* g = Ag + goff + (size_t)(hf * 64) * HD + kt * 64;
    _Float16* l = lds + buf * 16384 + (ldsC + hf * 64) * 8;
    gload16(g, l); gload16(g + 32, l + 8192);
  };
  auto stB = [&](int buf, int hf, int kt) {
    const _Float16* g = Bgp + goff + (size_t)(hf * 64) * HD + kt * 64;
    _Float16* l = lds + 32768 + buf * 16384 + (ldsC + hf * 64) * 8;
    gload16(g, l); gload16(g + 32, l + 8192);
  };

  f32x4 acc[8][4] = {};

  // Prologue: buf0 <- K-tile 0 (4 halves), buf1 <- K-tile 1 (3 halves).
  // vmcnt(6) = 3 calls in flight -> buf0 fully landed.
  stB(0, 0, 0); stB(0, 1, 0); stA(0, 0, 0); stA(0, 1, 0);
  stB(1, 0, 1); stB(1, 1, 1); stA(1, 0, 1);
  VM6();
  BAR();

#pragma unroll 1
  for (int i = 0; i < NIT; ++i) {
    const bool nl = (i < NIT - 1);
    const int kt1 = 2 * i + 1, kt2 = 2 * i + 2, kt3 = 2 * i + 3;
    f16x8 bfr[4][2];
    f16x8 a0, a1, a2, a3;

    // ---- p0..p3: read buf0 (K-tile 2i) ----
    stA(1, 1, kt1);                           // p0
    ALOAD(0, 0, 0); BLOAD(0);
    MFMAS(0, 0);
    LGKM0(); BAR();

    if (nl) stB(0, 0, kt2);                   // p1
    ALOAD(0, 0, 1);
    MFMAS(0, 1);
    LGKM0(); BAR();

    if (nl) stB(0, 1, kt2);                   // p2
    ALOAD(0, 1, 0);
    MFMAS(1, 0);
    LGKM0(); BAR();

    if (nl) stA(0, 0, kt2);                   // p3
    ALOAD(0, 1, 1);
    MFMAS(1, 1);
    LGKM0();
    if (nl) { VM6(); } else { VM0(); }        // buf1 content landed
    BAR();

    // ---- p4..p7: read buf1 (K-tile 2i+1) ----
    if (nl) stA(0, 1, kt2);                   // p4
    ALOAD(1, 0, 0); BLOAD(1);
    MFMAS(0, 0);
    LGKM0(); BAR();

    if (nl) stB(1, 0, kt3);                   // p5
    ALOAD(1, 0, 1);
    MFMAS(0, 1);
    LGKM0(); BAR();

    if (nl) stB(1, 1, kt3);                   // p6
    ALOAD(1, 1, 0);
    MFMAS(1, 0);
    LGKM0(); BAR();

    if (nl) stA(1, 0, kt3);                   // p7
    ALOAD(1, 1, 1);
    MFMAS(1, 1);
    LGKM0();
    if (nl) { VM6(); }                        // buf0 content landed
    BAR();
  }

  // Epilogue: C/D layout col = lane&15, row = (lane>>4)*4 + reg.
  // Non-temporal stores: keep the output stream from evicting A/W in L3.
  float bv[4];
#pragma unroll
  for (int nr = 0; nr < 4; ++nr)
    bv[nr] = bias[(ln0 + wn * 64 + nr * 16 + fr)];
#pragma unroll
  for (int mr = 0; mr < 8; ++mr) {
    const int r0 = m0 + wm * 128 + mr * 16 + fq * 4;
#pragma unroll
    for (int nr = 0; nr < 4; ++nr) {
      const int cg = n0 + wn * 64 + nr * 16 + fr;
      f32x4 v = acc[mr][nr];
#pragma unroll
      for (int r = 0; r < 4; ++r)
        __builtin_nontemporal_store(v[r] + bv[nr],
                                    &out[(size_t)(r0 + r) * NTOT + cg]);
    }
  }
}

// ---------------------------------------------------------------------------
extern "C" void kernel_launch(void* const* d_in, const int* in_sizes, int n_in,
                              void* d_out, int out_size, void* d_ws,
                              size_t ws_size, hipStream_t stream) {
  const float* x     = (const float*)d_in[0];
  const float* gamma = (const float*)d_in[1];
  const float* beta  = (const float*)d_in[2];
  const float* qw    = (const float*)d_in[3];
  const float* qb    = (const float*)d_in[4];
  const float* kw    = (const float*)d_in[5];
  const float* kbia  = (const float*)d_in[6];
  const float* vw    = (const float*)d_in[7];
  const float* vb    = (const float*)d_in[8];
  float* out = (float*)d_out;

  // Workspace: [0, 32M) normed fp16 [8192][2048]; [32M, 56M) W fp16 [3][2048][2048]
  char* ws = (char*)d_ws;
  _Float16* Ahp = (_Float16*)(ws);
  _Float16* Whp = (_Float16*)(ws + (size_t)MTOT * HD * 2);

  (void)hipFuncSetAttribute((const void*)qkv_gemm_kernel,
                            hipFuncAttributeMaxDynamicSharedMemorySize, 131072);

  ln_f16_kernel<<<MTOT, 256, 0, stream>>>(x, gamma, beta, Ahp);
  w_f16_kernel<<<dim3(1024, 3), 256, 0, stream>>>(qw, kw, vw, Whp);
  qkv_gemm_kernel<<<dim3(NTOT / 256, MTOT / 256), 512, 131072, stream>>>(
      Ahp, Whp, qb, kbia, vb, out);
}